// Round 5
// baseline (329.311 us; speedup 1.0000x reference)
//
#include <hip/hip_runtime.h>

// PatchMask: out[b,c,h,w] = x[b,c,h,w] * keep_mask[b, h/16, w/16]
// x: fp32 [64,3,512,512] (192 MiB)   keep_mask: int32 [64,32,32]
//
// Linear one-shot structure (the measured winner: R0/R2 = 319-321us vs
// predicated 327 / grid-stride 335 / wave-per-patch 328). Round-5
// single-variable change: flat x2 unroll — each thread handles float4s
// [base] and [base+256] (both instructions fully contiguous across the
// wave), doubling per-thread memory-level parallelism and halving block
// count, with NO loop-carried branch (R3's regressing variable).
//   - mask and x loads issue independently (predicated fetch-skip
//     regressed twice: R1 per-lane, R4 wave-uniform scatter)
//   - n4 = 12,582,912 = 24,576 blocks x 512 float4s exactly, no tail
// Traffic: 402 MB; floor ~64us at the 6.29 TB/s copy ceiling.

#define W_DIM 512
#define H_DIM 512
#define CH 3

__global__ __launch_bounds__(256) void PatchMask_kernel(
    const float4* __restrict__ x,
    const int* __restrict__ mask,
    float4* __restrict__ out,
    int n4)
{
    int base = blockIdx.x * 512 + threadIdx.x;

    int i0 = base;
    int i1 = base + 256;

    // --- index math for both (pure VALU, ~5% busy; not the bottleneck) ---
    int e0 = i0 << 2;
    int w0 = e0 & (W_DIM - 1);
    int h0 = (e0 >> 9) & (H_DIM - 1);
    int bc0 = e0 >> 18;
    int b0 = bc0 / CH;
    int mi0 = (b0 << 10) + ((h0 >> 4) << 5) + (w0 >> 4);

    int e1 = i1 << 2;
    int w1 = e1 & (W_DIM - 1);
    int h1 = (e1 >> 9) & (H_DIM - 1);
    int bc1 = e1 >> 18;
    int b1 = bc1 / CH;
    int mi1 = (b1 << 10) + ((h1 >> 4) << 5) + (w1 >> 4);

    // --- both x loads + both mask loads issue back-to-back (MLP=4) ---
    float4 v0 = x[i0];
    float4 v1 = x[i1];
    int m0 = mask[mi0];
    int m1 = mask[mi1];

    if (m0 == 0) { v0.x = 0.f; v0.y = 0.f; v0.z = 0.f; v0.w = 0.f; }
    if (m1 == 0) { v1.x = 0.f; v1.y = 0.f; v1.z = 0.f; v1.w = 0.f; }

    out[i0] = v0;
    out[i1] = v1;
}

extern "C" void kernel_launch(void* const* d_in, const int* in_sizes, int n_in,
                              void* d_out, int out_size, void* d_ws, size_t ws_size,
                              hipStream_t stream) {
    const float4* x   = (const float4*)d_in[0];
    const int* mask   = (const int*)d_in[1];
    float4* out       = (float4*)d_out;

    int n4 = out_size >> 2;          // 12,582,912 float4s
    int block = 256;
    int grid = n4 / (block * 2);     // 24,576 blocks, exact (no tail)

    PatchMask_kernel<<<grid, block, 0, stream>>>(x, mask, out, n4);
}

// Round 6
// 319.814 us; speedup vs baseline: 1.0297x; 1.0297x over previous
//
#include <hip/hip_runtime.h>

// PatchMask: out[b,c,h,w] = x[b,c,h,w] * keep_mask[b, h/16, w/16]
// x: fp32 [64,3,512,512] (192 MiB)   keep_mask: int32 [64,32,32] (L2-hot)
//
// FINAL — linear one-shot structure, the measured winner of the session:
//   R0/R2 (this kernel)          319-321 us
//   R1 per-lane fetch-skip       327 us  (mask->x dependent chain)
//   R3 grid-stride 2048 blocks   335 us  (lost TLP, loop overhead)
//   R4 wave-per-patch skip       328 us  (lost access contiguity)
//   R5 flat x2 unroll            329 us  (fewer waves, no BW gain)
// One float4 load + one L2-resident mask int + one float4 store per
// thread; maximal wave count; fully contiguous per-wave access. Every
// structural alternative measured 7-14 us worse. Kernel dispatch is at
// the practical mixed R/W streaming floor (~402 MB mandatory traffic);
// remaining bench time is harness-owned reset fills.

#define W_DIM 512
#define H_DIM 512
#define CH 3

__global__ __launch_bounds__(256) void PatchMask_kernel(
    const float4* __restrict__ x,
    const int* __restrict__ mask,
    float4* __restrict__ out,
    int n4)
{
    int i = blockIdx.x * blockDim.x + threadIdx.x;
    if (i >= n4) return;

    int e = i << 2;                 // element index
    int w = e & (W_DIM - 1);        // 512 = 2^9
    int h = (e >> 9) & (H_DIM - 1);
    int bc = e >> 18;               // b*3 + c
    int b = bc / CH;                // magic-mul

    int mi = (b << 10) + ((h >> 4) << 5) + (w >> 4);  // mask [B,32,32]

    float4 v = x[i];                // issues in parallel with mask load
    if (mask[mi] == 0) {
        v.x = 0.f; v.y = 0.f; v.z = 0.f; v.w = 0.f;
    }
    out[i] = v;
}

extern "C" void kernel_launch(void* const* d_in, const int* in_sizes, int n_in,
                              void* d_out, int out_size, void* d_ws, size_t ws_size,
                              hipStream_t stream) {
    const float4* x   = (const float4*)d_in[0];
    const int* mask   = (const int*)d_in[1];
    float4* out       = (float4*)d_out;

    int n4 = out_size >> 2;                      // 12,582,912 float4s
    int block = 256;
    int grid = (n4 + block - 1) / block;         // 49,152

    PatchMask_kernel<<<grid, block, 0, stream>>>(x, mask, out, n4);
}